// Round 2
// baseline (3432.022 us; speedup 1.0000x reference)
//
#include <hip/hip_runtime.h>
#include <hip/hip_bf16.h>
#include <cstdint>

// Problem constants
constexpr int kB = 512;      // batch
constexpr int kT = 80;       // encoder seq len
constexpr int kC = 512;      // in_channels
constexpr int kH = 256;      // hidden
constexpr int kV = 6625;     // classes
constexpr int kGIN = kC + kV; // 7137, gru_wih leading dim

typedef __attribute__((ext_vector_type(8))) short short8;
typedef __attribute__((ext_vector_type(4))) float floatx4;

__device__ __forceinline__ float fast_tanh(float x) {
  float e = __expf(2.f * x);
  return 1.f - 2.f / (e + 1.f);
}
__device__ __forceinline__ float fast_sig(float x) {
  return 1.f / (1.f + __expf(-x));
}

__device__ __forceinline__ void gld_lds16(const void* g, void* l) {
  __builtin_amdgcn_global_load_lds(
      (const __attribute__((address_space(1))) void*)(uintptr_t)g,
      (__attribute__((address_space(3))) void*)(uintptr_t)l, 16, 0, 0);
}

// ---------------------------------------------------------------------------
// fp32 -> bf16 conversion (gen_w)
// ---------------------------------------------------------------------------
__global__ __launch_bounds__(256) void cvt_bf16(const float* __restrict__ x,
                                                __hip_bfloat16* __restrict__ y,
                                                int n) {
  int i = blockIdx.x * 256 + threadIdx.x;
  if (i < n) y[i] = __float2bfloat16(x[i]);
}

// ---------------------------------------------------------------------------
// Copy wih[:, :512] into aligned buffer wihc[768][512] (ld 7137 -> 512).
// One element per thread; source reads coalesced within a row.
// ---------------------------------------------------------------------------
__global__ __launch_bounds__(256) void prep_wihc(const float* __restrict__ wih,
                                                 float* __restrict__ wihc) {
  int idx = blockIdx.x * 256 + threadIdx.x;   // over 768*512
  int r = idx >> 9, c = idx & 511;
  wihc[idx] = wih[(size_t)r * kGIN + c];
}

// ---------------------------------------------------------------------------
// proj = inputs @ i2h_w^T : [40960, 256], K=512. fp32, 128x128 tile,
// BK=16, 8x8 microtile (4 ds_read_b128 per 64 FMA).
// ---------------------------------------------------------------------------
__global__ __launch_bounds__(256) void gemm_proj(const float* __restrict__ A,
                                                 const float* __restrict__ W,
                                                 float* __restrict__ C) {
  __shared__ __align__(16) float As[16][132];
  __shared__ __align__(16) float Ws[16][132];
  const int tid = threadIdx.x;
  const int m0 = blockIdx.x * 128, n0 = blockIdx.y * 128;
  const int ty = tid >> 4, tx = tid & 15;
  float acc[8][8] = {};
  for (int k0 = 0; k0 < kC; k0 += 16) {
#pragma unroll
    for (int i = 0; i < 2; ++i) {
      int idx = tid * 2 + i;          // 0..511 over 128 rows x 4 quads
      int row = idx >> 2, q = idx & 3;
      float4 av = *(const float4*)(A + (size_t)(m0 + row) * kC + k0 + q * 4);
      As[q * 4 + 0][row] = av.x;
      As[q * 4 + 1][row] = av.y;
      As[q * 4 + 2][row] = av.z;
      As[q * 4 + 3][row] = av.w;
      float4 wv = *(const float4*)(W + (size_t)(n0 + row) * kC + k0 + q * 4);
      Ws[q * 4 + 0][row] = wv.x;
      Ws[q * 4 + 1][row] = wv.y;
      Ws[q * 4 + 2][row] = wv.z;
      Ws[q * 4 + 3][row] = wv.w;
    }
    __syncthreads();
#pragma unroll
    for (int k = 0; k < 16; ++k) {
      float4 a0 = *(const float4*)&As[k][ty * 8];
      float4 a1 = *(const float4*)&As[k][ty * 8 + 4];
      float4 w0 = *(const float4*)&Ws[k][tx * 8];
      float4 w1 = *(const float4*)&Ws[k][tx * 8 + 4];
      float a[8] = {a0.x, a0.y, a0.z, a0.w, a1.x, a1.y, a1.z, a1.w};
      float w[8] = {w0.x, w0.y, w0.z, w0.w, w1.x, w1.y, w1.z, w1.w};
#pragma unroll
      for (int i = 0; i < 8; ++i)
#pragma unroll
        for (int j = 0; j < 8; ++j) acc[i][j] += a[i] * w[j];
    }
    __syncthreads();
  }
#pragma unroll
  for (int i = 0; i < 8; ++i) {
    float* cp = C + (size_t)(m0 + ty * 8 + i) * kH + n0 + tx * 8;
    *(float4*)cp = make_float4(acc[i][0], acc[i][1], acc[i][2], acc[i][3]);
    *(float4*)(cp + 4) = make_float4(acc[i][4], acc[i][5], acc[i][6], acc[i][7]);
  }
}

// ---------------------------------------------------------------------------
// Fused attention step: per block b:
//   ph[j] = h2h_b[j] + sum_k h[b,k] h2h_w[j,k]
//   e[t]  = sum_h score_w[h] tanh(proj[b,t,h] + ph[h]);  softmax over T
//   ctx[b,c] = sum_t alpha_t inputs[b,t,c]
// ---------------------------------------------------------------------------
__global__ __launch_bounds__(256) void attn_step(
    const float* __restrict__ h, const float* __restrict__ h2h_w,
    const float* __restrict__ h2h_b, const float* __restrict__ score_w,
    const float* __restrict__ proj, const float* __restrict__ inputs,
    float* __restrict__ ctx) {
  __shared__ __align__(16) float h_s[kH];
  __shared__ __align__(16) float ph_s[kH];
  __shared__ __align__(16) float sw_s[kH];
  __shared__ float e_s[kT];
  const int b = blockIdx.x;
  const int tid = threadIdx.x;
  h_s[tid] = h[b * kH + tid];
  sw_s[tid] = score_w[tid];
  __syncthreads();
  // ph GEMV: thread tid -> output column tid
  {
    float acc = h2h_b[tid];
    const float* wr = h2h_w + (size_t)tid * kH;
#pragma unroll 4
    for (int k = 0; k < kH; k += 4) {
      float4 w = *(const float4*)(wr + k);
      float4 hv = *(const float4*)(h_s + k);
      acc += w.x * hv.x + w.y * hv.y + w.z * hv.z + w.w * hv.w;
    }
    ph_s[tid] = acc;
  }
  __syncthreads();
  const int wave = tid >> 6, lane = tid & 63;
  float4 p4 = ((const float4*)ph_s)[lane];
  float4 s4 = ((const float4*)sw_s)[lane];
  for (int t = wave; t < kT; t += 4) {
    const float* pp = proj + (size_t)(b * kT + t) * kH + lane * 4;
    float4 r = *(const float4*)pp;
    float part = fast_tanh(r.x + p4.x) * s4.x + fast_tanh(r.y + p4.y) * s4.y +
                 fast_tanh(r.z + p4.z) * s4.z + fast_tanh(r.w + p4.w) * s4.w;
#pragma unroll
    for (int off = 32; off > 0; off >>= 1) part += __shfl_xor(part, off);
    if (lane == 0) e_s[t] = part;
  }
  __syncthreads();
  if (wave == 0) {
    float v0 = e_s[lane];
    float v1 = (lane < kT - 64) ? e_s[64 + lane] : -1e30f;
    float mx = fmaxf(v0, v1);
#pragma unroll
    for (int off = 32; off > 0; off >>= 1) mx = fmaxf(mx, __shfl_xor(mx, off));
    float x0 = __expf(v0 - mx);
    float x1 = (lane < kT - 64) ? __expf(v1 - mx) : 0.f;
    float sm = x0 + x1;
#pragma unroll
    for (int off = 32; off > 0; off >>= 1) sm += __shfl_xor(sm, off);
    float inv = 1.f / sm;
    e_s[lane] = x0 * inv;
    if (lane < kT - 64) e_s[64 + lane] = x1 * inv;
  }
  __syncthreads();
  float c0 = 0.f, c1 = 0.f;
  const float* ib = inputs + (size_t)b * kT * kC;
  for (int t = 0; t < kT; ++t) {
    float a = e_s[t];
    c0 += a * ib[t * kC + tid];
    c1 += a * ib[t * kC + 256 + tid];
  }
  ctx[b * kC + tid] = c0;
  ctx[b * kC + 256 + tid] = c1;
}

// ---------------------------------------------------------------------------
// Fused GRU step. Grid (32, 8): block = 16 batch rows x 32 hidden cols.
// Thread: c = tid&31 (col), bp = tid>>5 (row pair). Computes gi (from aligned
// wihc + one-hot gather from wih), gh, and the full GRUCell update.
// ---------------------------------------------------------------------------
__global__ __launch_bounds__(256) void gru_step(
    const float* __restrict__ ctx, const float* __restrict__ hp,
    const float* __restrict__ wihc, const float* __restrict__ wih,
    const float* __restrict__ bih, const float* __restrict__ whh,
    const float* __restrict__ bhh, const int* __restrict__ tgt,
    int s, int S, float* __restrict__ hn, __hip_bfloat16* __restrict__ hidd) {
  __shared__ __align__(16) float ctx_s[16 * kC];
  __shared__ __align__(16) float h_s[16 * kH];
  const int tid = threadIdx.x;
  const int b0 = blockIdx.x * 16;
  const int c0 = blockIdx.y * 32;
#pragma unroll
  for (int i = 0; i < 8; ++i) {
    int f = tid + i * 256;          // f4 index over 16*512/4 = 2048
    int r = f >> 7, k4 = f & 127;
    ((float4*)ctx_s)[f] = *(const float4*)(ctx + (size_t)(b0 + r) * kC + k4 * 4);
  }
#pragma unroll
  for (int i = 0; i < 4; ++i) {
    int f = tid + i * 256;          // over 16*256/4 = 1024
    int r = f >> 6, k4 = f & 63;
    ((float4*)h_s)[f] = *(const float4*)(hp + (size_t)(b0 + r) * kH + k4 * 4);
  }
  __syncthreads();
  const int c = tid & 31;
  const int bp = tid >> 5;
  const int r0 = bp * 2, r1 = r0 + 1;
  const int hcol = c0 + c;
  const float* wr = wihc + (size_t)hcol * kC;
  const float* wz = wihc + (size_t)(hcol + 256) * kC;
  const float* wn = wihc + (size_t)(hcol + 512) * kC;
  float gir0 = 0, giz0 = 0, gin0 = 0, gir1 = 0, giz1 = 0, gin1 = 0;
  for (int k = 0; k < kC; k += 4) {
    float4 a = *(const float4*)(ctx_s + r0 * kC + k);
    float4 b4 = *(const float4*)(ctx_s + r1 * kC + k);
    float4 w1 = *(const float4*)(wr + k);
    float4 w2 = *(const float4*)(wz + k);
    float4 w3 = *(const float4*)(wn + k);
    gir0 += w1.x * a.x + w1.y * a.y + w1.z * a.z + w1.w * a.w;
    giz0 += w2.x * a.x + w2.y * a.y + w2.z * a.z + w2.w * a.w;
    gin0 += w3.x * a.x + w3.y * a.y + w3.z * a.z + w3.w * a.w;
    gir1 += w1.x * b4.x + w1.y * b4.y + w1.z * b4.z + w1.w * b4.w;
    giz1 += w2.x * b4.x + w2.y * b4.y + w2.z * b4.z + w2.w * b4.w;
    gin1 += w3.x * b4.x + w3.y * b4.y + w3.z * b4.z + w3.w * b4.w;
  }
  const float* vr = whh + (size_t)hcol * kH;
  const float* vz = whh + (size_t)(hcol + 256) * kH;
  const float* vn = whh + (size_t)(hcol + 512) * kH;
  float ghr0 = 0, ghz0 = 0, ghn0 = 0, ghr1 = 0, ghz1 = 0, ghn1 = 0;
  for (int k = 0; k < kH; k += 4) {
    float4 a = *(const float4*)(h_s + r0 * kH + k);
    float4 b4 = *(const float4*)(h_s + r1 * kH + k);
    float4 w1 = *(const float4*)(vr + k);
    float4 w2 = *(const float4*)(vz + k);
    float4 w3 = *(const float4*)(vn + k);
    ghr0 += w1.x * a.x + w1.y * a.y + w1.z * a.z + w1.w * a.w;
    ghz0 += w2.x * a.x + w2.y * a.y + w2.z * a.z + w2.w * a.w;
    ghn0 += w3.x * a.x + w3.y * a.y + w3.z * a.z + w3.w * a.w;
    ghr1 += w1.x * b4.x + w1.y * b4.y + w1.z * b4.z + w1.w * b4.w;
    ghz1 += w2.x * b4.x + w2.y * b4.y + w2.z * b4.z + w2.w * b4.w;
    ghn1 += w3.x * b4.x + w3.y * b4.y + w3.z * b4.z + w3.w * b4.w;
  }
  // biases + one-hot gather
  const float br = bih[hcol], bz = bih[hcol + 256], bn = bih[hcol + 512];
  const float dr = bhh[hcol], dz = bhh[hcol + 256], dn = bhh[hcol + 512];
  const int t0 = tgt[(b0 + r0) * S + s], t1 = tgt[(b0 + r1) * S + s];
  gir0 += wih[(size_t)hcol * kGIN + kC + t0] + br;
  giz0 += wih[(size_t)(hcol + 256) * kGIN + kC + t0] + bz;
  gin0 += wih[(size_t)(hcol + 512) * kGIN + kC + t0] + bn;
  gir1 += wih[(size_t)hcol * kGIN + kC + t1] + br;
  giz1 += wih[(size_t)(hcol + 256) * kGIN + kC + t1] + bz;
  gin1 += wih[(size_t)(hcol + 512) * kGIN + kC + t1] + bn;
  ghr0 += dr; ghz0 += dz; ghn0 += dn;
  ghr1 += dr; ghz1 += dz; ghn1 += dn;
  // GRU update
  {
    float rr = fast_sig(gir0 + ghr0);
    float zz = fast_sig(giz0 + ghz0);
    float nn = fast_tanh(gin0 + rr * ghn0);
    float hv = h_s[r0 * kH + hcol];
    float o = (1.f - zz) * nn + zz * hv;
    hn[(b0 + r0) * kH + hcol] = o;
    hidd[((size_t)(b0 + r0) * S + s) * kH + hcol] = __float2bfloat16(o);
  }
  {
    float rr = fast_sig(gir1 + ghr1);
    float zz = fast_sig(giz1 + ghz1);
    float nn = fast_tanh(gin1 + rr * ghn1);
    float hv = h_s[r1 * kH + hcol];
    float o = (1.f - zz) * nn + zz * hv;
    hn[(b0 + r1) * kH + hcol] = o;
    hidd[((size_t)(b0 + r1) * S + s) * kH + hcol] = __float2bfloat16(o);
  }
}

// ---------------------------------------------------------------------------
// Final GEMM, bf16 MFMA: C[M,N] = A[M,K] * W[N,K]^T + bias[n]
// 128x128 tile, BK=32, 4 waves in 2x2, 16x16x32 mfma, global_load_lds x16.
// ---------------------------------------------------------------------------
__global__ __launch_bounds__(256) void final_gemm(
    const __hip_bfloat16* __restrict__ A, const __hip_bfloat16* __restrict__ W,
    const float* __restrict__ bias, float* __restrict__ C, int M, int N, int K) {
  __shared__ __align__(16) short As[128 * 32];
  __shared__ __align__(16) short Ws[128 * 32];
  const int tid = threadIdx.x;
  const int wave = tid >> 6, lane = tid & 63;
  const int m0 = blockIdx.x * 128, n0 = blockIdx.y * 128;
  floatx4 acc[4][4] = {};
  const int lr = lane & 15;
  const int lkb = (lane >> 4) * 8;
  const int mloc = (wave & 1) * 64;
  const int nloc = (wave >> 1) * 64;
  const int srow = wave * 16 + (lane >> 2);
  const int skq = (lane & 3) * 8;
  for (int kt = 0; kt < K; kt += 32) {
#pragma unroll
    for (int r = 0; r < 2; ++r) {
      int rowA = r * 64 + srow;
      const __hip_bfloat16* ga = A + (size_t)(m0 + rowA) * K + kt + skq;
      gld_lds16(ga, (char*)As + (size_t)(r * 64 + wave * 16) * 64);
      int rowW = n0 + rowA;
      if (rowW > N - 1) rowW = N - 1;
      const __hip_bfloat16* gw = W + (size_t)rowW * K + kt + skq;
      gld_lds16(gw, (char*)Ws + (size_t)(r * 64 + wave * 16) * 64);
    }
    __syncthreads();
    short8 af[4], wf[4];
#pragma unroll
    for (int i = 0; i < 4; ++i)
      af[i] = *(const short8*)(As + (mloc + i * 16 + lr) * 32 + lkb);
#pragma unroll
    for (int j = 0; j < 4; ++j)
      wf[j] = *(const short8*)(Ws + (nloc + j * 16 + lr) * 32 + lkb);
#pragma unroll
    for (int i = 0; i < 4; ++i)
#pragma unroll
      for (int j = 0; j < 4; ++j)
        acc[i][j] = __builtin_amdgcn_mfma_f32_16x16x32_bf16(af[i], wf[j], acc[i][j], 0, 0, 0);
    __syncthreads();
  }
#pragma unroll
  for (int i = 0; i < 4; ++i) {
#pragma unroll
    for (int j = 0; j < 4; ++j) {
      int col = n0 + nloc + j * 16 + lr;
      if (col < N) {
        int rowb = m0 + mloc + i * 16 + ((lane >> 4) << 2);
        float bs = bias[col];
#pragma unroll
        for (int r = 0; r < 4; ++r)
          C[(size_t)(rowb + r) * N + col] = acc[i][j][r] + bs;
      }
    }
  }
}

// ---------------------------------------------------------------------------
extern "C" void kernel_launch(void* const* d_in, const int* in_sizes, int n_in,
                              void* d_out, int out_size, void* d_ws, size_t ws_size,
                              hipStream_t stream) {
  const float* inputs  = (const float*)d_in[0];
  const int*   targets = (const int*)d_in[1];
  const float* i2h_w   = (const float*)d_in[3];
  const float* h2h_w   = (const float*)d_in[4];
  const float* h2h_b   = (const float*)d_in[5];
  const float* score_w = (const float*)d_in[6];
  const float* gru_wih = (const float*)d_in[7];
  const float* gru_whh = (const float*)d_in[8];
  const float* gru_bih = (const float*)d_in[9];
  const float* gru_bhh = (const float*)d_in[10];
  const float* gen_w   = (const float*)d_in[11];
  const float* gen_b   = (const float*)d_in[12];
  float* out = (float*)d_out;
  const int S = out_size / (kB * kV);  // 25

  char* ws = (char*)d_ws;
  size_t off = 0;
  auto alloc = [&](size_t bytes) {
    void* p = ws + off;
    off += (bytes + 255) & ~(size_t)255;
    return p;
  };
  float* proj  = (float*)alloc((size_t)kB * kT * kH * 4);   // 41.9 MB
  float* ctx   = (float*)alloc((size_t)kB * kC * 4);        // 1 MB
  float* h0buf = (float*)alloc((size_t)kB * kH * 4);
  float* h1buf = (float*)alloc((size_t)kB * kH * 4);
  float* wihc  = (float*)alloc((size_t)768 * kC * 4);       // 1.5 MB
  __hip_bfloat16* hidd = (__hip_bfloat16*)alloc((size_t)kB * S * kH * 2);
  __hip_bfloat16* gw16 = (__hip_bfloat16*)alloc((size_t)kV * kH * 2);

  hipMemsetAsync(h0buf, 0, (size_t)kB * kH * 4, stream);

  cvt_bf16<<<dim3((kV * kH + 255) / 256), 256, 0, stream>>>(gen_w, gw16, kV * kH);
  prep_wihc<<<dim3(768 * kC / 256), 256, 0, stream>>>(gru_wih, wihc);

  gemm_proj<<<dim3(kB * kT / 128, kH / 128), 256, 0, stream>>>(inputs, i2h_w, proj);

  for (int s = 0; s < S; ++s) {
    float* hp = (s & 1) ? h1buf : h0buf;
    float* hn = (s & 1) ? h0buf : h1buf;
    attn_step<<<dim3(kB), 256, 0, stream>>>(hp, h2h_w, h2h_b, score_w, proj,
                                            inputs, ctx);
    gru_step<<<dim3(kB / 16, kH / 32), 256, 0, stream>>>(
        ctx, hp, wihc, gru_wih, gru_bih, gru_whh, gru_bhh, targets, s, S,
        hn, hidd);
  }

  final_gemm<<<dim3(kB * S / 128, (kV + 127) / 128), 256, 0, stream>>>(
      hidd, gw16, gen_b, out, kB * S, kV, kH);
}